// Round 10
// baseline (302.629 us; speedup 1.0000x reference)
//
#include <hip/hip_runtime.h>
#include <math.h>

#define N 16384
#define D 23
#define K 16
#define NG 32               // cells per dim
#define NCELL (NG * NG * NG)
#define GINV 4.0f           // 1/cell width (cell = 0.25)
#define GOFF 4.0f           // domain [-4,4)
#define CAP 64              // per-wave candidate buffer (one key per lane)

__device__ __forceinline__ int cellof(float v) {
  int b = (int)((v + GOFF) * GINV);
  return b < 0 ? 0 : (b > NG - 1 ? NG - 1 : b);
}
// order-preserving float->u32 (monotone, invertible)
__device__ __forceinline__ unsigned enc32(float f) {
  unsigned u = __float_as_uint(f);
  return (u & 0x80000000u) ? ~u : (u | 0x80000000u);
}
__device__ __forceinline__ float dec32(unsigned u) {
  return __uint_as_float((u & 0x80000000u) ? (u & 0x7fffffffu) : ~u);
}

// ---------------------------------------------------------------------------
// Kernel 1: s = x@W_s + b_s, h = x@W_h + b_h; pack s4={sx,sy,sz,sq}, h4;
//           3-D cell histogram. Coalesced x via LDS staging.
// ---------------------------------------------------------------------------
__global__ __launch_bounds__(64) void prep_kernel(
    const float* __restrict__ x, const float* __restrict__ Ws,
    const float* __restrict__ bs, const float* __restrict__ Wh,
    const float* __restrict__ bh, float4* __restrict__ s4,
    float4* __restrict__ h4, int* __restrict__ hist) {
  __shared__ float lWs[D * 3], lWh[D * 3], lbs[3], lbh[3];
  __shared__ float xl[64 * D];
  for (int t = threadIdx.x; t < D * 3; t += 64) {
    lWs[t] = Ws[t];
    lWh[t] = Wh[t];
  }
  if (threadIdx.x < 3) {
    lbs[threadIdx.x] = bs[threadIdx.x];
    lbh[threadIdx.x] = bh[threadIdx.x];
  }
  const float* xb = x + (size_t)blockIdx.x * 64 * D;
  for (int j = threadIdx.x; j < 64 * D; j += 64) xl[j] = xb[j];
  __syncthreads();

  int i = blockIdx.x * 64 + threadIdx.x;
  float a0 = 0.f, a1 = 0.f, a2 = 0.f;
  float g0 = 0.f, g1 = 0.f, g2 = 0.f;
#pragma unroll
  for (int d = 0; d < D; ++d) {
    float xv = xl[threadIdx.x * D + d];
    a0 = fmaf(xv, lWs[d * 3 + 0], a0);
    a1 = fmaf(xv, lWs[d * 3 + 1], a1);
    a2 = fmaf(xv, lWs[d * 3 + 2], a2);
    g0 = fmaf(xv, lWh[d * 3 + 0], g0);
    g1 = fmaf(xv, lWh[d * 3 + 1], g1);
    g2 = fmaf(xv, lWh[d * 3 + 2], g2);
  }
  float s0 = __fadd_rn(a0, lbs[0]);
  float s1 = __fadd_rn(a1, lbs[1]);
  float s2 = __fadd_rn(a2, lbs[2]);
  float sq = fmaf(s2, s2, fmaf(s1, s1, __fmul_rn(s0, s0)));
  s4[i] = make_float4(s0, s1, s2, sq);
  h4[i] = make_float4(__fadd_rn(g0, lbh[0]), __fadd_rn(g1, lbh[1]),
                      __fadd_rn(g2, lbh[2]), 0.f);
  int cid = (cellof(s2) << 10) | (cellof(s1) << 5) | cellof(s0);
  atomicAdd(&hist[cid], 1);
}

// ---------------------------------------------------------------------------
// Kernel 2: exclusive prefix sum of hist[32768] -> offs[32769]. One block.
// ---------------------------------------------------------------------------
__global__ __launch_bounds__(1024) void scan_kernel(const int* __restrict__ hist,
                                                    int* __restrict__ offs) {
  __shared__ int wsum[16];
  int t = threadIdx.x;
  int loc[32];
  int s = 0;
#pragma unroll
  for (int j = 0; j < 32; ++j) {
    loc[j] = hist[t * 32 + j];
    s += loc[j];
  }
  int lane = t & 63, wid = t >> 6;
  int v = s;
#pragma unroll
  for (int off = 1; off < 64; off <<= 1) {
    int o = __shfl_up(v, off);
    if (lane >= off) v += o;
  }
  if (lane == 63) wsum[wid] = v;
  __syncthreads();
  if (t == 0) {
    int acc = 0;
#pragma unroll
    for (int w = 0; w < 16; ++w) {
      int tmp = wsum[w];
      wsum[w] = acc;
      acc += tmp;
    }
  }
  __syncthreads();
  int run = wsum[wid] + (v - s);  // global exclusive prefix
#pragma unroll
  for (int j = 0; j < 32; ++j) {
    offs[t * 32 + j] = run;
    run += loc[j];
  }
  if (t == 1023) offs[NCELL] = run;  // == N
}

// ---------------------------------------------------------------------------
// Kernel 3: scatter into cell-sorted layout (+ sorted h, orig index)
// ---------------------------------------------------------------------------
__global__ __launch_bounds__(64) void scatter_kernel(
    const float4* __restrict__ s4, const float4* __restrict__ h4,
    const int* __restrict__ offs, int* __restrict__ cnt2,
    float4* __restrict__ s4s, float4* __restrict__ h4s,
    int* __restrict__ idxs) {
  int i = blockIdx.x * 64 + threadIdx.x;
  float4 s = s4[i];
  int cid = (cellof(s.z) << 10) | (cellof(s.y) << 5) | cellof(s.x);
  int pos = offs[cid] + atomicAdd(&cnt2[cid], 1);
  s4s[pos] = s;
  h4s[pos] = h4[i];
  idxs[pos] = i;
}

// ---------------------------------------------------------------------------
// Kernel 4: kNN + aggregate + fused output GEMM/beta. ONE QUERY PER WAVE.
// Query assignment STRIDED (P = w*4096 + blockIdx) to decorrelate difficulty
// across blocks (anti-straggler). Scan: per cz-layer one contiguous span;
// coalesced 64-lane loads; d2<=r^2 ballot-compacted into per-wave LDS buf
// (cap 64) + exact count. Accept 16<=cnt<=64 (exact certificate). Radius
// control: cube-root density targeting with bracket (rlo,rhi) -> ~1 rescan.
// Selection: u64-key bitonic sort of 64. Epilogue: aggregation butterfly,
// latent row on lanes 0..22, z via 6-level butterfly dot.
// ---------------------------------------------------------------------------
__global__ __launch_bounds__(256) void knn_kernel(
    const float4* __restrict__ s4s, const float4* __restrict__ h4s,
    const int* __restrict__ idxs, const int* __restrict__ offs,
    const float* __restrict__ x, const float* __restrict__ Wo1,
    const float* __restrict__ Wo2, const float* __restrict__ bo2,
    const float* __restrict__ Wb, const float* __restrict__ bb,
    float* __restrict__ out) {
  __shared__ float bufd[4][CAP];
  __shared__ int bufi[4][CAP];
  __shared__ float lWo1[D * D], lWo2[6 * D], lbo2[D], lWb[D], lbb[1];
  {
    int t = threadIdx.x;
    for (int j = t; j < D * D; j += 256) lWo1[j] = Wo1[j];
    for (int j = t; j < 6 * D; j += 256) lWo2[j] = Wo2[j];
    if (t < D) {
      lbo2[t] = bo2[t];
      lWb[t] = Wb[t];
    }
    if (t == 0) lbb[0] = bb[0];
  }
  __syncthreads();

  int w = threadIdx.x >> 6;
  int lane = threadIdx.x & 63;
  int P = w * 4096 + blockIdx.x;  // strided: decorrelate difficulty
  float4 si = s4s[P];
  float sqi = si.w;
  // Gaussian 16-NN radius estimate (x1.25). No cap: overshoot handled by
  // cube-root bisect-down (1 cheap rescan), undershoot was the tail killer.
  float r = fminf(0.1925f * __expf(sqi * 0.16666667f), 4.0f);
  float rlo = 0.f, rhi = 0.f;

  int cnt = 0;
  for (int it = 0; it < 16; ++it) {
    float r2 = __fmul_rn(r, r);
    int cx0 = cellof(si.x - r), cx1 = cellof(si.x + r);
    int cy0 = cellof(si.y - r), cy1 = cellof(si.y + r);
    int cz0 = cellof(si.z - r), cz1 = cellof(si.z + r);
    int nz = cz1 - cz0 + 1;
    int sp_st = 0, sp_en = 0;
    if (lane < nz) {
      int cz = cz0 + lane;
      sp_st = offs[(cz << 10) | (cy0 << 5) | cx0];
      sp_en = offs[((cz << 10) | (cy1 << 5)) + cx1 + 1];
    }
    cnt = 0;
    for (int l = 0; l < nz; ++l) {
      int st = __shfl(sp_st, l);
      int en = __shfl(sp_en, l);
      for (int p0 = st; p0 < en; p0 += 64) {
        int p = p0 + lane;
        bool pv = (p < en);
        int pc = pv ? p : (en - 1);
        float4 sj = s4s[pc];
        float dot = fmaf(si.z, sj.z, fmaf(si.y, sj.y, __fmul_rn(si.x, sj.x)));
        float d2 = __fsub_rn(__fadd_rn(sqi, sj.w), __fmul_rn(2.0f, dot));
        bool pred = pv && (d2 <= r2);
        unsigned long long mk = __ballot(pred);
        int below = __builtin_amdgcn_mbcnt_hi(
            (unsigned)(mk >> 32), __builtin_amdgcn_mbcnt_lo((unsigned)mk, 0));
        int slot = cnt + below;
        if (pred && slot < CAP) {
          bufd[w][slot] = d2;
          bufi[w][slot] = pc;
        }
        cnt += (int)__popcll(mk);
      }
    }
    if (cnt >= K && cnt <= CAP) break;  // exact certificate
    if (it >= 12 && cnt >= K) break;    // force-accept (P~0 path)
    if (cnt < K) {
      rlo = r;
      if (rhi > 0.f) {
        r = 0.5f * (rlo + rhi);
      } else {
        float g = __powf(44.0f / fmaxf((float)cnt, 2.0f), 0.33333334f);
        r = __fmul_rn(r, fminf(g, 2.0f));
      }
    } else {  // cnt > CAP: shrink toward density target, stay inside bracket
      rhi = r;
      float rt = __fmul_rn(r, __powf(44.0f / (float)cnt, 0.33333334f));
      if (rt <= rlo) rt = 0.5f * (rlo + rhi);
      r = rt;
    }
  }

  // ---- selection: u64-key bitonic sort of 64; ranks 0..15 -> lanes 0..15 ----
  int M = cnt < CAP ? cnt : CAP;
  unsigned long long key = ~0ull;
  if (lane < M)
    key = ((unsigned long long)enc32(bufd[w][lane]) << 32) |
          (unsigned)bufi[w][lane];
#pragma unroll
  for (int kk = 2; kk <= 64; kk <<= 1) {
#pragma unroll
    for (int j = kk >> 1; j > 0; j >>= 1) {
      unsigned long long other = __shfl_xor(key, j);
      bool keepMin = ((lane & j) == 0) == ((lane & kk) == 0);
      unsigned long long mn = key < other ? key : other;
      unsigned long long mx = key < other ? other : key;
      key = keepMin ? mn : mx;
    }
  }
  float sel_d = dec32((unsigned)(key >> 32));
  int sel_i = ((int)(unsigned)(key & 0xffffffffu)) & (N - 1);

  // ---- aggregation butterfly within 16-lane groups ----
  float wwt = expf(-10.0f * fmaxf(sel_d, 0.f));
  float4 hh = h4s[sel_i];
  float m0 = __fmul_rn(hh.x, wwt);
  float m1 = __fmul_rn(hh.y, wwt);
  float m2 = __fmul_rn(hh.z, wwt);
  float x0 = m0, x1 = m1, x2 = m2;
#pragma unroll
  for (int s = 1; s < K; s <<= 1) {
    m0 += __shfl_xor(m0, s);
    m1 += __shfl_xor(m1, s);
    m2 += __shfl_xor(m2, s);
    x0 = fmaxf(x0, __shfl_xor(x0, s));
    x1 = fmaxf(x1, __shfl_xor(x1, s));
    x2 = fmaxf(x2, __shfl_xor(x2, s));
  }
  // broadcast group-0 (the true top-16 group) aggregates to all lanes
  const float inv = 1.0f / 16.0f;
  float ag[6];
  ag[0] = __shfl(m0, 0) * inv;
  ag[1] = __shfl(m1, 0) * inv;
  ag[2] = __shfl(m2, 0) * inv;
  ag[3] = __shfl(x0, 0);
  ag[4] = __shfl(x1, 0);
  ag[5] = __shfl(x2, 0);

  // ---- fused output: latent row on lanes 0..22; z via butterfly dot ----
  int oq = idxs[P];
  const float* xq = x + (size_t)oq * D;
  int o = lane < D ? lane : 0;
  float acc = 0.f;
#pragma unroll
  for (int d = 0; d < D; ++d) acc = fmaf(xq[d], lWo1[d * D + o], acc);
  float b2 = 0.f;
#pragma unroll
  for (int p = 0; p < 6; ++p) b2 = fmaf(ag[p], lWo2[p * D + o], b2);
  b2 = __fadd_rn(b2, lbo2[o]);
  float lat = __fadd_rn(acc, b2);
  if (lane < D) out[(size_t)N + (size_t)oq * D + lane] = lat;
  float zp = (lane < D) ? __fmul_rn(lat, lWb[lane]) : 0.f;
#pragma unroll
  for (int s = 1; s < 64; s <<= 1) zp += __shfl_xor(zp, s);
  if (lane == 0) {
    float z = __fadd_rn(zp, lbb[0]);
    float beta = 1.0f / (1.0f + expf(-z));
    out[oq] = fminf(fmaxf(beta, 1e-6f), 1.0f - 1e-6f);
  }
}

// ---------------------------------------------------------------------------
extern "C" void kernel_launch(void* const* d_in, const int* in_sizes, int n_in,
                              void* d_out, int out_size, void* d_ws,
                              size_t ws_size, hipStream_t stream) {
  const float* x = (const float*)d_in[0];
  const float* Ws = (const float*)d_in[1];
  const float* bs = (const float*)d_in[2];
  const float* Wh = (const float*)d_in[3];
  const float* bh = (const float*)d_in[4];
  const float* Wo1 = (const float*)d_in[5];
  const float* Wo2 = (const float*)d_in[6];
  const float* bo2 = (const float*)d_in[7];
  const float* Wb = (const float*)d_in[8];
  const float* bb = (const float*)d_in[9];
  float* out = (float*)d_out;

  // ws (floats): s4[N*4] | h4[N*4] | s4s[N*4] | h4s[N*4] | idxs[N]i |
  // hist[32768]i | cnt2[32768]i | offs[32769]i   (~1.5 MB)
  float* ws = (float*)d_ws;
  float4* s4 = (float4*)ws;
  float4* h4 = (float4*)(ws + (size_t)N * 4);
  float4* s4s = (float4*)(ws + (size_t)N * 8);
  float4* h4s = (float4*)(ws + (size_t)N * 12);
  int* idxs = (int*)(ws + (size_t)N * 16);
  int* hist = idxs + N;
  int* cnt2 = hist + NCELL;
  int* offs = cnt2 + NCELL;

  // zero hist+cnt2 (contiguous) without a kernel launch
  hipMemsetAsync(hist, 0, (size_t)2 * NCELL * sizeof(int), stream);
  prep_kernel<<<N / 64, 64, 0, stream>>>(x, Ws, bs, Wh, bh, s4, h4, hist);
  scan_kernel<<<1, 1024, 0, stream>>>(hist, offs);
  scatter_kernel<<<N / 64, 64, 0, stream>>>(s4, h4, offs, cnt2, s4s, h4s,
                                            idxs);
  knn_kernel<<<N / 4, 256, 0, stream>>>(s4s, h4s, idxs, offs, x, Wo1, Wo2,
                                        bo2, Wb, bb, out);
}

// Round 11
// 207.378 us; speedup vs baseline: 1.4593x; 1.4593x over previous
//
#include <hip/hip_runtime.h>
#include <math.h>

#define N 16384
#define D 23
#define K 16
#define NG 32               // cells per dim
#define NCELL (NG * NG * NG)
#define GINV 4.0f           // 1/cell width (cell = 0.25)
#define GOFF 4.0f           // domain [-4,4)
#define CAP 64              // per-wave candidate buffer (one key per lane)

__device__ __forceinline__ int cellof(float v) {
  int b = (int)((v + GOFF) * GINV);
  return b < 0 ? 0 : (b > NG - 1 ? NG - 1 : b);
}
// order-preserving float->u32 (monotone, invertible)
__device__ __forceinline__ unsigned enc32(float f) {
  unsigned u = __float_as_uint(f);
  return (u & 0x80000000u) ? ~u : (u | 0x80000000u);
}
__device__ __forceinline__ float dec32(unsigned u) {
  return __uint_as_float((u & 0x80000000u) ? (u & 0x7fffffffu) : ~u);
}

// ---------------------------------------------------------------------------
// Kernel 1: s = x@W_s + b_s, h = x@W_h + b_h; pack s4={sx,sy,sz,sq}, h4;
//           3-D cell histogram. Coalesced x via LDS staging.
// ---------------------------------------------------------------------------
__global__ __launch_bounds__(64) void prep_kernel(
    const float* __restrict__ x, const float* __restrict__ Ws,
    const float* __restrict__ bs, const float* __restrict__ Wh,
    const float* __restrict__ bh, float4* __restrict__ s4,
    float4* __restrict__ h4, int* __restrict__ hist) {
  __shared__ float lWs[D * 3], lWh[D * 3], lbs[3], lbh[3];
  __shared__ float xl[64 * D];
  for (int t = threadIdx.x; t < D * 3; t += 64) {
    lWs[t] = Ws[t];
    lWh[t] = Wh[t];
  }
  if (threadIdx.x < 3) {
    lbs[threadIdx.x] = bs[threadIdx.x];
    lbh[threadIdx.x] = bh[threadIdx.x];
  }
  const float* xb = x + (size_t)blockIdx.x * 64 * D;
  for (int j = threadIdx.x; j < 64 * D; j += 64) xl[j] = xb[j];
  __syncthreads();

  int i = blockIdx.x * 64 + threadIdx.x;
  float a0 = 0.f, a1 = 0.f, a2 = 0.f;
  float g0 = 0.f, g1 = 0.f, g2 = 0.f;
#pragma unroll
  for (int d = 0; d < D; ++d) {
    float xv = xl[threadIdx.x * D + d];
    a0 = fmaf(xv, lWs[d * 3 + 0], a0);
    a1 = fmaf(xv, lWs[d * 3 + 1], a1);
    a2 = fmaf(xv, lWs[d * 3 + 2], a2);
    g0 = fmaf(xv, lWh[d * 3 + 0], g0);
    g1 = fmaf(xv, lWh[d * 3 + 1], g1);
    g2 = fmaf(xv, lWh[d * 3 + 2], g2);
  }
  float s0 = __fadd_rn(a0, lbs[0]);
  float s1 = __fadd_rn(a1, lbs[1]);
  float s2 = __fadd_rn(a2, lbs[2]);
  float sq = fmaf(s2, s2, fmaf(s1, s1, __fmul_rn(s0, s0)));
  s4[i] = make_float4(s0, s1, s2, sq);
  h4[i] = make_float4(__fadd_rn(g0, lbh[0]), __fadd_rn(g1, lbh[1]),
                      __fadd_rn(g2, lbh[2]), 0.f);
  int cid = (cellof(s2) << 10) | (cellof(s1) << 5) | cellof(s0);
  atomicAdd(&hist[cid], 1);
}

// ---------------------------------------------------------------------------
// Kernel 2: exclusive prefix sum of hist[32768] -> offs[32769]. One block.
// ---------------------------------------------------------------------------
__global__ __launch_bounds__(1024) void scan_kernel(const int* __restrict__ hist,
                                                    int* __restrict__ offs) {
  __shared__ int wsum[16];
  int t = threadIdx.x;
  int loc[32];
  int s = 0;
#pragma unroll
  for (int j = 0; j < 32; ++j) {
    loc[j] = hist[t * 32 + j];
    s += loc[j];
  }
  int lane = t & 63, wid = t >> 6;
  int v = s;
#pragma unroll
  for (int off = 1; off < 64; off <<= 1) {
    int o = __shfl_up(v, off);
    if (lane >= off) v += o;
  }
  if (lane == 63) wsum[wid] = v;
  __syncthreads();
  if (t == 0) {
    int acc = 0;
#pragma unroll
    for (int w = 0; w < 16; ++w) {
      int tmp = wsum[w];
      wsum[w] = acc;
      acc += tmp;
    }
  }
  __syncthreads();
  int run = wsum[wid] + (v - s);  // global exclusive prefix
#pragma unroll
  for (int j = 0; j < 32; ++j) {
    offs[t * 32 + j] = run;
    run += loc[j];
  }
  if (t == 1023) offs[NCELL] = run;  // == N
}

// ---------------------------------------------------------------------------
// Kernel 3: scatter into cell-sorted layout (+ sorted h, orig index)
// ---------------------------------------------------------------------------
__global__ __launch_bounds__(64) void scatter_kernel(
    const float4* __restrict__ s4, const float4* __restrict__ h4,
    const int* __restrict__ offs, int* __restrict__ cnt2,
    float4* __restrict__ s4s, float4* __restrict__ h4s,
    int* __restrict__ idxs) {
  int i = blockIdx.x * 64 + threadIdx.x;
  float4 s = s4[i];
  int cid = (cellof(s.z) << 10) | (cellof(s.y) << 5) | cellof(s.x);
  int pos = offs[cid] + atomicAdd(&cnt2[cid], 1);
  s4s[pos] = s;
  h4s[pos] = h4[i];
  idxs[pos] = i;
}

// ---------------------------------------------------------------------------
// Kernel 4: kNN + aggregate + fused output GEMM/beta. ONE QUERY PER WAVE,
// consecutive queries per block (sorted order: L1 window sharing + natural
// load balance through the 4096-deep block queue).
// Scan: per cz-layer one contiguous span; coalesced 64-lane loads; d2<=r^2
// ballot-compacted into per-wave LDS buf (cap 64) + exact counts at THREE
// nested radii {r, 0.7r, 0.49r}. Accept 16<=cnt<=64 (exact certificate).
// Overshoot (cnt>64): sub-counts certify a smaller radius -> at most one
// guaranteed-accept rescan (L2-warm), or a tight bracket. Undershoot: x1.7
// grow / bisect. Replaces the blind bisection cascade.
// Selection: u64-key bitonic sort of 64. Epilogue: aggregation butterfly,
// latent row on lanes 0..22, z via 6-level butterfly dot.
// ---------------------------------------------------------------------------
__global__ __launch_bounds__(256) void knn_kernel(
    const float4* __restrict__ s4s, const float4* __restrict__ h4s,
    const int* __restrict__ idxs, const int* __restrict__ offs,
    const float* __restrict__ x, const float* __restrict__ Wo1,
    const float* __restrict__ Wo2, const float* __restrict__ bo2,
    const float* __restrict__ Wb, const float* __restrict__ bb,
    float* __restrict__ out) {
  __shared__ float bufd[4][CAP];
  __shared__ int bufi[4][CAP];
  __shared__ float lWo1[D * D], lWo2[6 * D], lbo2[D], lWb[D], lbb[1];
  {
    int t = threadIdx.x;
    for (int j = t; j < D * D; j += 256) lWo1[j] = Wo1[j];
    for (int j = t; j < 6 * D; j += 256) lWo2[j] = Wo2[j];
    if (t < D) {
      lbo2[t] = bo2[t];
      lWb[t] = Wb[t];
    }
    if (t == 0) lbb[0] = bb[0];
  }
  __syncthreads();

  int w = threadIdx.x >> 6;
  int lane = threadIdx.x & 63;
  int P = blockIdx.x * 4 + w;  // consecutive sorted queries (reverted)
  float4 si = s4s[P];
  float sqi = si.w;
  float r = fminf(0.1925f * __expf(sqi * 0.16666667f), 0.8f);
  float rlo = 0.f, rhi = 0.f;

  int cnt = 0;
  for (int it = 0; it < 16; ++it) {
    float rb = __fmul_rn(r, 0.7f);
    float rc = __fmul_rn(r, 0.49f);
    float r2a = __fmul_rn(r, r);
    float r2b = __fmul_rn(rb, rb);
    float r2c = __fmul_rn(rc, rc);
    int cx0 = cellof(si.x - r), cx1 = cellof(si.x + r);
    int cy0 = cellof(si.y - r), cy1 = cellof(si.y + r);
    int cz0 = cellof(si.z - r), cz1 = cellof(si.z + r);
    int nz = cz1 - cz0 + 1;
    int sp_st = 0, sp_en = 0;
    if (lane < nz) {
      int cz = cz0 + lane;
      sp_st = offs[(cz << 10) | (cy0 << 5) | cx0];
      sp_en = offs[((cz << 10) | (cy1 << 5)) + cx1 + 1];
    }
    cnt = 0;
    int cntb = 0, cntc = 0;
    for (int l = 0; l < nz; ++l) {
      int st = __shfl(sp_st, l);
      int en = __shfl(sp_en, l);
      for (int p0 = st; p0 < en; p0 += 64) {
        int p = p0 + lane;
        bool pv = (p < en);
        int pc = pv ? p : (en - 1);
        float4 sj = s4s[pc];
        float dot = fmaf(si.z, sj.z, fmaf(si.y, sj.y, __fmul_rn(si.x, sj.x)));
        float d2 = __fsub_rn(__fadd_rn(sqi, sj.w), __fmul_rn(2.0f, dot));
        bool pa = pv && (d2 <= r2a);
        unsigned long long mk = __ballot(pa);
        int below = __builtin_amdgcn_mbcnt_hi(
            (unsigned)(mk >> 32), __builtin_amdgcn_mbcnt_lo((unsigned)mk, 0));
        int slot = cnt + below;
        if (pa && slot < CAP) {
          bufd[w][slot] = d2;
          bufi[w][slot] = pc;
        }
        cnt += (int)__popcll(mk);
        cntb += (int)__popcll(__ballot(pv && (d2 <= r2b)));
        cntc += (int)__popcll(__ballot(pv && (d2 <= r2c)));
      }
    }
    if (cnt >= K && cnt <= CAP) break;  // exact certificate
    if (it >= 12 && cnt >= K) break;    // force-accept (P~0 path)
    if (cnt < K) {
      rlo = r;
      r = (rhi > 0.f) ? 0.5f * (rlo + rhi) : __fmul_rn(r, 1.7f);
    } else {
      // overshoot: certified sub-radius or tight bracket
      rhi = r;
      if (cntb < K) {          // window inside (0.7r, r): bisect tight
        rlo = fmaxf(rlo, rb);
        r = 0.5f * (rlo + rhi);
      } else if (cntb <= CAP) {
        r = rb;                // guaranteed accept next scan
      } else {
        rhi = rb;
        if (cntc < K) {        // window inside (0.49r, 0.7r): bisect tight
          rlo = fmaxf(rlo, rc);
          r = 0.5f * (rlo + rhi);
        } else if (cntc <= CAP) {
          r = rc;              // guaranteed accept next scan
        } else {               // still >64 at 0.49r: density-targeted shrink
          rhi = rc;
          float rt = __fmul_rn(rc, __powf(44.0f / (float)cntc, 0.33333334f));
          r = (rt > rlo) ? rt : 0.5f * (rlo + rhi);
        }
      }
    }
  }

  // ---- selection: u64-key bitonic sort of 64; ranks 0..15 -> lanes 0..15 ----
  int M = cnt < CAP ? cnt : CAP;
  unsigned long long key = ~0ull;
  if (lane < M)
    key = ((unsigned long long)enc32(bufd[w][lane]) << 32) |
          (unsigned)bufi[w][lane];
#pragma unroll
  for (int kk = 2; kk <= 64; kk <<= 1) {
#pragma unroll
    for (int j = kk >> 1; j > 0; j >>= 1) {
      unsigned long long other = __shfl_xor(key, j);
      bool keepMin = ((lane & j) == 0) == ((lane & kk) == 0);
      unsigned long long mn = key < other ? key : other;
      unsigned long long mx = key < other ? other : key;
      key = keepMin ? mn : mx;
    }
  }
  float sel_d = dec32((unsigned)(key >> 32));
  int sel_i = ((int)(unsigned)(key & 0xffffffffu)) & (N - 1);

  // ---- aggregation butterfly within 16-lane groups ----
  float wwt = expf(-10.0f * fmaxf(sel_d, 0.f));
  float4 hh = h4s[sel_i];
  float m0 = __fmul_rn(hh.x, wwt);
  float m1 = __fmul_rn(hh.y, wwt);
  float m2 = __fmul_rn(hh.z, wwt);
  float x0 = m0, x1 = m1, x2 = m2;
#pragma unroll
  for (int s = 1; s < K; s <<= 1) {
    m0 += __shfl_xor(m0, s);
    m1 += __shfl_xor(m1, s);
    m2 += __shfl_xor(m2, s);
    x0 = fmaxf(x0, __shfl_xor(x0, s));
    x1 = fmaxf(x1, __shfl_xor(x1, s));
    x2 = fmaxf(x2, __shfl_xor(x2, s));
  }
  // broadcast group-0 (the true top-16 group) aggregates to all lanes
  const float inv = 1.0f / 16.0f;
  float ag[6];
  ag[0] = __shfl(m0, 0) * inv;
  ag[1] = __shfl(m1, 0) * inv;
  ag[2] = __shfl(m2, 0) * inv;
  ag[3] = __shfl(x0, 0);
  ag[4] = __shfl(x1, 0);
  ag[5] = __shfl(x2, 0);

  // ---- fused output: latent row on lanes 0..22; z via butterfly dot ----
  int oq = idxs[P];
  const float* xq = x + (size_t)oq * D;
  int o = lane < D ? lane : 0;
  float acc = 0.f;
#pragma unroll
  for (int d = 0; d < D; ++d) acc = fmaf(xq[d], lWo1[d * D + o], acc);
  float b2 = 0.f;
#pragma unroll
  for (int p = 0; p < 6; ++p) b2 = fmaf(ag[p], lWo2[p * D + o], b2);
  b2 = __fadd_rn(b2, lbo2[o]);
  float lat = __fadd_rn(acc, b2);
  if (lane < D) out[(size_t)N + (size_t)oq * D + lane] = lat;
  float zp = (lane < D) ? __fmul_rn(lat, lWb[lane]) : 0.f;
#pragma unroll
  for (int s = 1; s < 64; s <<= 1) zp += __shfl_xor(zp, s);
  if (lane == 0) {
    float z = __fadd_rn(zp, lbb[0]);
    float beta = 1.0f / (1.0f + expf(-z));
    out[oq] = fminf(fmaxf(beta, 1e-6f), 1.0f - 1e-6f);
  }
}

// ---------------------------------------------------------------------------
extern "C" void kernel_launch(void* const* d_in, const int* in_sizes, int n_in,
                              void* d_out, int out_size, void* d_ws,
                              size_t ws_size, hipStream_t stream) {
  const float* x = (const float*)d_in[0];
  const float* Ws = (const float*)d_in[1];
  const float* bs = (const float*)d_in[2];
  const float* Wh = (const float*)d_in[3];
  const float* bh = (const float*)d_in[4];
  const float* Wo1 = (const float*)d_in[5];
  const float* Wo2 = (const float*)d_in[6];
  const float* bo2 = (const float*)d_in[7];
  const float* Wb = (const float*)d_in[8];
  const float* bb = (const float*)d_in[9];
  float* out = (float*)d_out;

  // ws (floats): s4[N*4] | h4[N*4] | s4s[N*4] | h4s[N*4] | idxs[N]i |
  // hist[32768]i | cnt2[32768]i | offs[32769]i   (~1.5 MB)
  float* ws = (float*)d_ws;
  float4* s4 = (float4*)ws;
  float4* h4 = (float4*)(ws + (size_t)N * 4);
  float4* s4s = (float4*)(ws + (size_t)N * 8);
  float4* h4s = (float4*)(ws + (size_t)N * 12);
  int* idxs = (int*)(ws + (size_t)N * 16);
  int* hist = idxs + N;
  int* cnt2 = hist + NCELL;
  int* offs = cnt2 + NCELL;

  // zero hist+cnt2 (contiguous) without a kernel launch
  hipMemsetAsync(hist, 0, (size_t)2 * NCELL * sizeof(int), stream);
  prep_kernel<<<N / 64, 64, 0, stream>>>(x, Ws, bs, Wh, bh, s4, h4, hist);
  scan_kernel<<<1, 1024, 0, stream>>>(hist, offs);
  scatter_kernel<<<N / 64, 64, 0, stream>>>(s4, h4, offs, cnt2, s4s, h4s,
                                            idxs);
  knn_kernel<<<N / 4, 256, 0, stream>>>(s4s, h4s, idxs, offs, x, Wo1, Wo2,
                                        bo2, Wb, bb, out);
}